// Round 4
// baseline (2621.787 us; speedup 1.0000x reference)
//
#include <hip/hip_runtime.h>

typedef unsigned char  u8;
typedef unsigned short u16;
typedef unsigned int   u32;

#define NN   16384     // nodes
#define EE   262144    // edges
#define RR   9         // relations
#define DIN  384
#define DH   768
#define KSU  3456      // RR*DIN
#define KS   3488      // KSU + 9 cnt cols + pad to 32

typedef float  f32x4 __attribute__((ext_vector_type(4)));
typedef float  f32x2 __attribute__((ext_vector_type(2)));
typedef __bf16 b16x8 __attribute__((ext_vector_type(8)));

__device__ __forceinline__ u16 f2bf(float f){
  u32 u = __builtin_bit_cast(u32, f);
  u += 0x7fffu + ((u >> 16) & 1u);          // RNE
  return (u16)(u >> 16);
}
__device__ __forceinline__ float bf2f(u16 h){
  u32 u = ((u32)h) << 16;
  return __builtin_bit_cast(float, u);
}
__device__ __forceinline__ float bflo(u32 u){ return __builtin_bit_cast(float, u << 16); }
__device__ __forceinline__ float bfhi(u32 u){ return __builtin_bit_cast(float, u & 0xffff0000u); }
__device__ __forceinline__ u32 pk2(float a, float b){
  return (u32)f2bf(a) | ((u32)f2bf(b) << 16);
}
// async global->LDS, 16B per lane; LDS dest = wave-uniform base + lane*16
__device__ __forceinline__ void gll16(const void* g, void* l){
  __builtin_amdgcn_global_load_lds((const __attribute__((address_space(1))) void*)g,
                                   (__attribute__((address_space(3))) void*)l, 16, 0, 0);
}

// ---------------- CSR build ----------------
__global__ void k_count(const int* __restrict__ dst, int* __restrict__ counts){
  const int e = blockIdx.x*256 + threadIdx.x;
  if (e < EE) atomicAdd(&counts[dst[e]], 1);
}

__global__ __launch_bounds__(1024) void k_scan(const int* __restrict__ counts,
                                               int* __restrict__ starts,
                                               int* __restrict__ cursor){
  __shared__ int tot[1024];
  const int t = threadIdx.x;
  int loc[16]; int s = 0;
  #pragma unroll
  for (int j=0;j<16;j++){ loc[j] = counts[t*16+j]; s += loc[j]; }
  tot[t] = s;
  __syncthreads();
  for (int o=1;o<1024;o<<=1){
    int v = (t>=o) ? tot[t-o] : 0;
    __syncthreads();
    tot[t] += v;
    __syncthreads();
  }
  int run = tot[t] - s;  // exclusive prefix
  #pragma unroll
  for (int j=0;j<16;j++){ starts[t*16+j] = run; cursor[t*16+j] = run; run += loc[j]; }
  if (t == 1023) starts[NN] = run;
}

// scatter edges into CSR order; emit pre-gathered src/rtype arrays
__global__ void k_place(const int* __restrict__ src, const int* __restrict__ dst,
                        const int* __restrict__ et, int* __restrict__ cursor,
                        int* __restrict__ srcp, int* __restrict__ rp){
  const int e = blockIdx.x*256 + threadIdx.x;
  if (e < EE){
    const int p = atomicAdd(&cursor[dst[e]], 1);
    srcp[p] = src[e];
    rp[p]   = et[e];
  }
}

// ---------------- conversions to bf16 ----------------
__global__ void k_convX(const float* __restrict__ x, u32* __restrict__ xb){
  const int idx = blockIdx.x*256 + threadIdx.x;   // pairs; NN*DIN/2 total
  const f32x2 v = ((const f32x2*)x)[idx];
  xb[idx] = pk2(v.x, v.y);
}

// W_stack[hh][k]: k<3456 -> rel_W[r=k/384][hh][k%384]; 3456..3464 -> rel_b[r][hh]; else 0
__global__ void k_convW1(const float* __restrict__ rW, const float* __restrict__ rb,
                         u16* __restrict__ Wst){
  const int hh = blockIdx.y;
  const int k  = blockIdx.x*256 + threadIdx.x;
  if (k >= KS) return;
  float v;
  if (k < KSU){ const int r = k / DIN; const int d = k - r*DIN;
                v = rW[((long)r*DH + hh)*DIN + d]; }
  else if (k < KSU + RR){ const int r = k - KSU; v = rb[(long)r*DH + hh]; }
  else v = 0.f;
  Wst[(long)hh*KS + k] = f2bf(v);
}

__global__ void k_convW2(const float* __restrict__ lW, const float* __restrict__ sW,
                         u16* __restrict__ WB){
  const int idx = blockIdx.x*256 + threadIdx.x;  // exactly 1179648 threads
  const float v = (idx < DH*DH) ? lW[idx] : sW[idx - DH*DH];
  WB[idx] = f2bf(v);
}

// ---------------- phase1 fused: wave per dst node, bf16 gather, VGPR acc ----
// s[i, r*384+d] = sum_{p in seg(i)} (dot(x[i],x[srcp])/nc[r]) * x[srcp, d]
// s[i, 3456+r]  = sum norm ; rest of row = 0
__global__ __launch_bounds__(256, 4) void k_phase1f(const u32* __restrict__ xb,
                                                    const int* __restrict__ srcp,
                                                    const int* __restrict__ rp,
                                                    const float* __restrict__ nc,
                                                    const int* __restrict__ starts,
                                                    u16* __restrict__ s){
  const int w = threadIdx.x >> 6, l = threadIdx.x & 63;
  const int i = blockIdx.x*4 + w;
  const u32* xr = xb + (long)i*192;             // 384 bf16 = 192 u32
  float xdf[6];
  {
    const u32 a = xr[l], b = xr[64+l], c = xr[128+l];
    xdf[0]=bflo(a); xdf[1]=bfhi(a); xdf[2]=bflo(b);
    xdf[3]=bfhi(b); xdf[4]=bflo(c); xdf[5]=bfhi(c);
  }
  float ncv[RR];
  #pragma unroll
  for (int r=0;r<RR;r++) ncv[r] = 1.0f / nc[r];
  float acc[RR][6];
  float cacc[RR];
  #pragma unroll
  for (int r=0;r<RR;r++){
    cacc[r] = 0.f;
    #pragma unroll
    for (int j=0;j<6;j++) acc[r][j] = 0.f;
  }
  const int e0 = starts[i], np = starts[i+1] - e0;
  u32 a0[2], a1[2], a2[2]; int rr[2];
  #pragma unroll
  for (int q=0;q<2;q++){
    a0[q]=0; a1[q]=0; a2[q]=0; rr[q]=0;
    if (q < np){
      const u32* xs = xb + (long)srcp[e0+q]*192;
      a0[q]=xs[l]; a1[q]=xs[64+l]; a2[q]=xs[128+l]; rr[q]=rp[e0+q];
    }
  }
  for (int p=0; p<np; ++p){
    const int b = p & 1;
    const u32 c0=a0[b], c1=a1[b], c2=a2[b];
    const int r = rr[b];
    if (p+2 < np){                       // prefetch two edges ahead
      const u32* xs = xb + (long)srcp[e0+p+2]*192;
      a0[b]=xs[l]; a1[b]=xs[64+l]; a2[b]=xs[128+l]; rr[b]=rp[e0+p+2];
    }
    float cf[6];
    cf[0]=bflo(c0); cf[1]=bfhi(c0); cf[2]=bflo(c1);
    cf[3]=bfhi(c1); cf[4]=bflo(c2); cf[5]=bfhi(c2);
    float part = xdf[0]*cf[0] + xdf[1]*cf[1] + xdf[2]*cf[2]
               + xdf[3]*cf[3] + xdf[4]*cf[4] + xdf[5]*cf[5];
    #pragma unroll
    for (int o=32;o;o>>=1) part += __shfl_xor(part, o);
    #define UPD(R) { const float nm = part*ncv[R]; cacc[R] += nm; \
      acc[R][0] += nm*cf[0]; acc[R][1] += nm*cf[1]; acc[R][2] += nm*cf[2]; \
      acc[R][3] += nm*cf[3]; acc[R][4] += nm*cf[4]; acc[R][5] += nm*cf[5]; }
    switch (r){                           // wave-uniform branch
      case 0: UPD(0); break; case 1: UPD(1); break; case 2: UPD(2); break;
      case 3: UPD(3); break; case 4: UPD(4); break; case 5: UPD(5); break;
      case 6: UPD(6); break; case 7: UPD(7); break; default: UPD(8); break;
    }
    #undef UPD
  }
  u16* srow = s + (long)i*KS;
  #pragma unroll
  for (int r=0;r<RR;r++){
    #pragma unroll
    for (int seg=0;seg<3;seg++)
      ((u32*)(srow + r*DIN + seg*128))[l] = pk2(acc[r][seg*2], acc[r][seg*2+1]);
  }
  float cv = 0.f;
  #pragma unroll
  for (int r=0;r<RR;r++) cv = (l == r) ? cacc[r] : cv;
  if (l < 32) srow[KSU + l] = f2bf(l < RR ? cv : 0.f);
}

// ---------------- m97-style bf16 GEMM: C = A * B^T (both K-major) ----------------
// grid: x = M-tile (fast), y = N-tile  -> same-A blocks land on same XCD (id%8)
// MODE 0: O0 = relu(C) bf16, stride DH           (gemm1: x1)
// MODE 1: n<768 -> O0 = C+b0[n]; else O1 = C+b1  (gemm2: hm / selfx)
template<int MODE>
__global__ __launch_bounds__(256, 2)
void k_gemm_bt(const u16* __restrict__ A, const u16* __restrict__ B,
               int M, int N, int K,
               u16* __restrict__ O0, u16* __restrict__ O1,
               const float* __restrict__ b0, const float* __restrict__ b1)
{
  __shared__ __align__(16) u16 As[128*32];
  __shared__ __align__(16) u16 Bs[128*32];
  const int t  = threadIdx.x;
  const int wv = t >> 6;
  const int ln = t & 63;
  const int wm = wv >> 1, wn = wv & 1;
  const long m0 = (long)blockIdx.x * 128;
  const long n0 = (long)blockIdx.y * 128;

  const int srow  = ln >> 2;         // staging: lane -> row within 16-row segment
  const int skcol = (ln & 3) * 8;    // k element offset (8 bf16 = 16B)

  f32x4 acc[4][4];
  #pragma unroll
  for (int i=0;i<4;i++)
    #pragma unroll
    for (int j=0;j<4;j++) acc[i][j] = {0.f,0.f,0.f,0.f};

  const int fr = ln & 15, fq = ln >> 4;
  const int nk = K >> 5;
  for (int kb=0; kb<nk; ++kb){
    const long k0 = (long)kb * 32;
    #pragma unroll
    for (int q=0;q<2;q++){
      const int seg = wv*2 + q;
      const int row = seg*16 + srow;
      gll16(A + (m0 + row)*(long)K + k0 + skcol, &As[seg*512]);
      gll16(B + (n0 + row)*(long)K + k0 + skcol, &Bs[seg*512]);
    }
    __syncthreads();
    b16x8 av[4], bv[4];
    #pragma unroll
    for (int i=0;i<4;i++){
      av[i] = *(const b16x8*)&As[(wm*64 + i*16 + fr)*32 + fq*8];
      bv[i] = *(const b16x8*)&Bs[(wn*64 + i*16 + fr)*32 + fq*8];
    }
    #pragma unroll
    for (int i=0;i<4;i++)
      #pragma unroll
      for (int j=0;j<4;j++)
        acc[i][j] = __builtin_amdgcn_mfma_f32_16x16x32_bf16(av[i], bv[j], acc[i][j], 0, 0, 0);
    __syncthreads();
  }

  #pragma unroll
  for (int i=0;i<4;i++){
    #pragma unroll
    for (int j=0;j<4;j++){
      #pragma unroll
      for (int r=0;r<4;r++){
        const long m = m0 + wm*64 + i*16 + fq*4 + r;   // C row = quad*4+reg
        const long n = n0 + wn*64 + j*16 + fr;         // C col = lane&15
        float v = acc[i][j][r];
        if (MODE == 0){
          v = v > 0.f ? v : 0.f;
          O0[m*DH + n] = f2bf(v);
        } else {
          if (n < DH) O0[m*DH + n]      = f2bf(v + b0[n]);
          else        O1[m*DH + (n-DH)] = f2bf(v + b1[n-DH]);
        }
      }
    }
  }
}

// ---------------- phase2 + mean-pool fused ----------------
// per node i: v = relu( sum_{p in seg(i)} hm[srcp[p]] + sfx[i] ); pooled += v
// x2 never materialized.
__global__ __launch_bounds__(256, 4) void k_phase2(const u32* __restrict__ hm32,
                                                   const u32* __restrict__ sfx32,
                                                   const int* __restrict__ srcp,
                                                   const int* __restrict__ starts,
                                                   float* __restrict__ pooled){
  const int w = threadIdx.x >> 6, l = threadIdx.x & 63;
  const int i = blockIdx.x*4 + w;
  const int t = threadIdx.x;
  __shared__ float pl[DH];
  #pragma unroll
  for (int k=0;k<3;k++) pl[t + 256*k] = 0.f;
  __syncthreads();

  float a[12];
  #pragma unroll
  for (int j=0;j<12;j++) a[j] = 0.f;
  const int e0 = starts[i], np = starts[i+1] - e0;
  u32 pf[2][6];
  #pragma unroll
  for (int q=0;q<2;q++){
    #pragma unroll
    for (int j=0;j<6;j++) pf[q][j] = 0;
    if (q < np){
      const u32* hr = hm32 + (long)srcp[e0+q]*384;
      #pragma unroll
      for (int j=0;j<6;j++) pf[q][j] = hr[l + 64*j];
    }
  }
  for (int p=0; p<np; ++p){
    const int b = p & 1;
    u32 c[6];
    #pragma unroll
    for (int j=0;j<6;j++) c[j] = pf[b][j];
    if (p+2 < np){
      const u32* hr = hm32 + (long)srcp[e0+p+2]*384;
      #pragma unroll
      for (int j=0;j<6;j++) pf[b][j] = hr[l + 64*j];
    }
    #pragma unroll
    for (int j=0;j<6;j++){ a[2*j] += bflo(c[j]); a[2*j+1] += bfhi(c[j]); }
  }
  const u32* sr = sfx32 + (long)i*384;
  #pragma unroll
  for (int j=0;j<6;j++){
    const u32 sv = sr[l + 64*j];
    float v0 = a[2*j]   + bflo(sv);
    float v1 = a[2*j+1] + bfhi(sv);
    v0 = v0 > 0.f ? v0 : 0.f;
    v1 = v1 > 0.f ? v1 : 0.f;
    atomicAdd(&pl[2*l   + 128*j], v0);    // LDS atomic across the 4 waves
    atomicAdd(&pl[2*l+1 + 128*j], v1);
  }
  __syncthreads();
  #pragma unroll
  for (int k=0;k<3;k++) atomicAdd(&pooled[t + 256*k], pl[t + 256*k]);
}

__global__ __launch_bounds__(256) void k_final(const float* __restrict__ pooled,
                                               const float* __restrict__ oW,
                                               const float* __restrict__ ob,
                                               float* __restrict__ out){
  __shared__ float red[256];
  const int t = threadIdx.x;
  for (int c=0;c<5;c++){
    float p = 0.f;
    for (int h=t; h<DH; h+=256) p += pooled[h]*oW[c*DH + h];
    red[t] = p; __syncthreads();
    for (int o=128;o;o>>=1){ if (t<o) red[t]+=red[t+o]; __syncthreads(); }
    if (t == 0) out[c] = red[0]*(1.f/(float)NN) + ob[c];
    __syncthreads();
  }
}

// ---------------- launch ----------------
extern "C" void kernel_launch(void* const* d_in, const int* in_sizes, int n_in,
                              void* d_out, int out_size, void* d_ws, size_t ws_size,
                              hipStream_t stream)
{
  (void)in_sizes; (void)n_in; (void)out_size; (void)ws_size;
  const float* x     = (const float*)d_in[0];
  const int*   ei    = (const int*)  d_in[1];   // [2][E]: row0=src, row1=dst
  const int*   et    = (const int*)  d_in[2];
  const float* relW  = (const float*)d_in[3];
  const float* relb  = (const float*)d_in[4];
  const float* nc    = (const float*)d_in[5];
  const float* linW  = (const float*)d_in[6];
  const float* linb  = (const float*)d_in[7];
  const float* selfW = (const float*)d_in[8];
  const float* selfb = (const float*)d_in[9];
  const float* outW  = (const float*)d_in[10];
  const float* outb  = (const float*)d_in[11];
  float* out = (float*)d_out;

  // workspace layout (256B aligned); xb aliases x1 (dead until gemm1 writes it);
  // hm/sfx alias S (dead after gemm1)
  u8* w = (u8*)d_ws;
  int*   counts = (int*)(w + 0);              // 64 KB
  int*   starts = (int*)(w + 65536);          // 16385*4
  int*   cursor = (int*)(w + 131328);         // 64 KB
  int*   srcp   = (int*)(w + 196864);         // 1 MB
  int*   rp     = (int*)(w + 2294016);        // 1 MB
  u16*   Wst    = (u16*)(w + 4391168);        // 768*3488*2  = 5.36 MB
  u16*   WB     = (u16*)(w + 9748736);        // 1536*768*2  = 2.36 MB
  u16*   x1     = (u16*)(w + 12108032);       // 16384*768*2 = 25.2 MB
  u32*   xb     = (u32*)x1;                   // alias: 12.6 MB, dead before gemm1
  float* pooled = (float*)(w + 37273856);     // 3 KB
  u16*   S      = (u16*)(w + 37276928);       // 16384*3488*2 = 114.3 MB
  u16*   hm     = S;                          // alias: 25.2 MB
  u16*   sfx    = (u16*)(w + 37276928 + 25165824);

  const int* esrc = ei;
  const int* edst = ei + EE;

  hipMemsetAsync(counts, 0, NN*sizeof(int), stream);
  hipMemsetAsync(pooled, 0, DH*sizeof(float), stream);

  k_count <<<EE/256, 256, 0, stream>>>(edst, counts);
  k_scan  <<<1, 1024, 0, stream>>>(counts, starts, cursor);
  k_place <<<EE/256, 256, 0, stream>>>(esrc, edst, et, cursor, srcp, rp);
  k_convX <<<(NN*DIN/2)/256, 256, 0, stream>>>(x, xb);
  k_convW1<<<dim3(14, DH), 256, 0, stream>>>(relW, relb, Wst);
  k_convW2<<<(2*DH*DH)/256, 256, 0, stream>>>(linW, selfW, WB);
  k_phase1f<<<NN/4, 256, 0, stream>>>(xb, srcp, rp, nc, starts, S);
  k_gemm_bt<0><<<dim3(NN/128, DH/128), 256, 0, stream>>>(
      S, Wst, NN, DH, KS, x1, (u16*)nullptr, (const float*)nullptr, (const float*)nullptr);
  k_gemm_bt<1><<<dim3(NN/128, 2*DH/128), 256, 0, stream>>>(
      x1, WB, NN, 2*DH, DH, hm, sfx, linb, selfb);
  k_phase2<<<NN/4, 256, 0, stream>>>((const u32*)hm, (const u32*)sfx, srcp, starts, pooled);
  k_final <<<1, 256, 0, stream>>>(pooled, outW, outb, out);
}

// Round 5
// 680.494 us; speedup vs baseline: 3.8528x; 3.8528x over previous
//
#include <hip/hip_runtime.h>

typedef unsigned char  u8;
typedef unsigned short u16;
typedef unsigned int   u32;

#define NN   16384     // nodes
#define EE   262144    // edges
#define RR   9         // relations
#define DIN  384
#define DH   768
#define KSU  3456      // RR*DIN
#define KS   3488      // KSU + 9 cnt cols + pad to 32

typedef float  f32x4 __attribute__((ext_vector_type(4)));
typedef float  f32x2 __attribute__((ext_vector_type(2)));
typedef __bf16 b16x8 __attribute__((ext_vector_type(8)));

__device__ __forceinline__ u16 f2bf(float f){
  u32 u = __builtin_bit_cast(u32, f);
  u += 0x7fffu + ((u >> 16) & 1u);          // RNE
  return (u16)(u >> 16);
}
__device__ __forceinline__ float bf2f(u16 h){
  u32 u = ((u32)h) << 16;
  return __builtin_bit_cast(float, u);
}
__device__ __forceinline__ float bflo(u32 u){ return __builtin_bit_cast(float, u << 16); }
__device__ __forceinline__ float bfhi(u32 u){ return __builtin_bit_cast(float, u & 0xffff0000u); }
__device__ __forceinline__ u32 pk2(float a, float b){
  return (u32)f2bf(a) | ((u32)f2bf(b) << 16);
}
// async global->LDS, 16B per lane; LDS dest = wave-uniform base + lane*16
__device__ __forceinline__ void gll16(const void* g, void* l){
  __builtin_amdgcn_global_load_lds((const __attribute__((address_space(1))) void*)g,
                                   (__attribute__((address_space(3))) void*)l, 16, 0, 0);
}

// ---------------- CSR build ----------------
__global__ void k_count(const int* __restrict__ dst, int* __restrict__ counts){
  const int e = blockIdx.x*256 + threadIdx.x;
  if (e < EE) atomicAdd(&counts[dst[e]], 1);
}

__global__ __launch_bounds__(1024) void k_scan(const int* __restrict__ counts,
                                               int* __restrict__ starts,
                                               int* __restrict__ cursor){
  __shared__ int tot[1024];
  const int t = threadIdx.x;
  int loc[16]; int s = 0;
  #pragma unroll
  for (int j=0;j<16;j++){ loc[j] = counts[t*16+j]; s += loc[j]; }
  tot[t] = s;
  __syncthreads();
  for (int o=1;o<1024;o<<=1){
    int v = (t>=o) ? tot[t-o] : 0;
    __syncthreads();
    tot[t] += v;
    __syncthreads();
  }
  int run = tot[t] - s;  // exclusive prefix
  #pragma unroll
  for (int j=0;j<16;j++){ starts[t*16+j] = run; cursor[t*16+j] = run; run += loc[j]; }
  if (t == 1023) starts[NN] = run;
}

// scatter edges into CSR order; emit pre-gathered src/rtype arrays
__global__ void k_place(const int* __restrict__ src, const int* __restrict__ dst,
                        const int* __restrict__ et, int* __restrict__ cursor,
                        int* __restrict__ srcp, int* __restrict__ rp){
  const int e = blockIdx.x*256 + threadIdx.x;
  if (e < EE){
    const int p = atomicAdd(&cursor[dst[e]], 1);
    srcp[p] = src[e];
    rp[p]   = et[e];
  }
}

// ---------------- conversions to bf16 ----------------
__global__ void k_convX(const float* __restrict__ x, u32* __restrict__ xb){
  const int idx = blockIdx.x*256 + threadIdx.x;   // pairs; NN*DIN/2 total
  const f32x2 v = ((const f32x2*)x)[idx];
  xb[idx] = pk2(v.x, v.y);
}

// W_stack[hh][k]: k<3456 -> rel_W[r=k/384][hh][k%384]; 3456..3464 -> rel_b[r][hh]; else 0
__global__ void k_convW1(const float* __restrict__ rW, const float* __restrict__ rb,
                         u16* __restrict__ Wst){
  const int hh = blockIdx.y;
  const int k  = blockIdx.x*256 + threadIdx.x;
  if (k >= KS) return;
  float v;
  if (k < KSU){ const int r = k / DIN; const int d = k - r*DIN;
                v = rW[((long)r*DH + hh)*DIN + d]; }
  else if (k < KSU + RR){ const int r = k - KSU; v = rb[(long)r*DH + hh]; }
  else v = 0.f;
  Wst[(long)hh*KS + k] = f2bf(v);
}

__global__ void k_convW2(const float* __restrict__ lW, const float* __restrict__ sW,
                         u16* __restrict__ WB){
  const int idx = blockIdx.x*256 + threadIdx.x;  // exactly 1179648 threads
  const float v = (idx < DH*DH) ? lW[idx] : sW[idx - DH*DH];
  WB[idx] = f2bf(v);
}

// ---------------- phase1 fused: wave per dst node, bf16 gather, VGPR acc ----
// s[i, r*384+d] = sum_{p in seg(i)} (dot(x[i],x[srcp])/nc[r]) * x[srcp, d]
// s[i, 3456+r]  = sum norm ; rest of row = 0
// NOTE: launch_bounds(256,2) — cap 256 VGPR. (256,4) made the compiler spill
// the 54-reg accumulator to scratch (R4: 10.9 GB HBM, 5x regression).
// Prefetch slots A/B are explicit scalars (constant indices only — runtime-
// indexed register arrays get demoted to scratch).
__global__ __launch_bounds__(256, 2) void k_phase1f(const u32* __restrict__ xb,
                                                    const int* __restrict__ srcp,
                                                    const int* __restrict__ rp,
                                                    const float* __restrict__ nc,
                                                    const int* __restrict__ starts,
                                                    u16* __restrict__ s){
  const int w = threadIdx.x >> 6, l = threadIdx.x & 63;
  const int i = blockIdx.x*4 + w;
  const u32* xr = xb + (long)i*192;             // 384 bf16 = 192 u32
  float xdf[6];
  {
    const u32 a = xr[l], b = xr[64+l], c = xr[128+l];
    xdf[0]=bflo(a); xdf[1]=bfhi(a); xdf[2]=bflo(b);
    xdf[3]=bfhi(b); xdf[4]=bflo(c); xdf[5]=bfhi(c);
  }
  float ncv[RR];
  #pragma unroll
  for (int r=0;r<RR;r++) ncv[r] = 1.0f / nc[r];
  float acc[RR][6];
  float cacc[RR];
  #pragma unroll
  for (int r=0;r<RR;r++){
    cacc[r] = 0.f;
    #pragma unroll
    for (int j=0;j<6;j++) acc[r][j] = 0.f;
  }
  const int e0 = starts[i], np = starts[i+1] - e0;

  // slot A: even-index edges; slot B: odd-index edges
  u32 A0=0,A1=0,A2=0,B0=0,B1=0,B2=0; int Ar=0, Br=0;
  if (np > 0){
    const u32* xs = xb + (long)srcp[e0]*192;
    A0=xs[l]; A1=xs[64+l]; A2=xs[128+l]; Ar=rp[e0];
  }
  if (np > 1){
    const u32* xs = xb + (long)srcp[e0+1]*192;
    B0=xs[l]; B1=xs[64+l]; B2=xs[128+l]; Br=rp[e0+1];
  }

  #define UPD(R,CF,NM) { cacc[R] += NM; \
    acc[R][0] += NM*CF[0]; acc[R][1] += NM*CF[1]; acc[R][2] += NM*CF[2]; \
    acc[R][3] += NM*CF[3]; acc[R][4] += NM*CF[4]; acc[R][5] += NM*CF[5]; }
  #define SW(R,CF,PART) { const float nm_ = (PART)*ncv[R]; UPD(R,CF,nm_) }

  for (int p=0; p<np; p+=2){
    const bool h2 = (p+1 < np);
    const u32 a0=A0, a1=A1, a2=A2; const int ra=Ar;
    const u32 b0=B0, b1=B1, b2=B2; const int rb=Br;
    if (p+2 < np){                      // refill A with edge p+2
      const u32* xs = xb + (long)srcp[e0+p+2]*192;
      A0=xs[l]; A1=xs[64+l]; A2=xs[128+l]; Ar=rp[e0+p+2];
    }
    if (p+3 < np){                      // refill B with edge p+3
      const u32* xs = xb + (long)srcp[e0+p+3]*192;
      B0=xs[l]; B1=xs[64+l]; B2=xs[128+l]; Br=rp[e0+p+3];
    }
    float fa[6], fb[6];
    fa[0]=bflo(a0); fa[1]=bfhi(a0); fa[2]=bflo(a1);
    fa[3]=bfhi(a1); fa[4]=bflo(a2); fa[5]=bfhi(a2);
    fb[0]=bflo(b0); fb[1]=bfhi(b0); fb[2]=bflo(b1);
    fb[3]=bfhi(b1); fb[4]=bflo(b2); fb[5]=bfhi(b2);
    float pa = xdf[0]*fa[0] + xdf[1]*fa[1] + xdf[2]*fa[2]
             + xdf[3]*fa[3] + xdf[4]*fa[4] + xdf[5]*fa[5];
    float pb = xdf[0]*fb[0] + xdf[1]*fb[1] + xdf[2]*fb[2]
             + xdf[3]*fb[3] + xdf[4]*fb[4] + xdf[5]*fb[5];
    #pragma unroll
    for (int o=32;o;o>>=1){             // two interleaved butterfly chains
      pa += __shfl_xor(pa, o);
      pb += __shfl_xor(pb, o);
    }
    switch (ra){                        // wave-uniform
      case 0: SW(0,fa,pa); break; case 1: SW(1,fa,pa); break;
      case 2: SW(2,fa,pa); break; case 3: SW(3,fa,pa); break;
      case 4: SW(4,fa,pa); break; case 5: SW(5,fa,pa); break;
      case 6: SW(6,fa,pa); break; case 7: SW(7,fa,pa); break;
      default: SW(8,fa,pa); break;
    }
    if (h2){
      switch (rb){
        case 0: SW(0,fb,pb); break; case 1: SW(1,fb,pb); break;
        case 2: SW(2,fb,pb); break; case 3: SW(3,fb,pb); break;
        case 4: SW(4,fb,pb); break; case 5: SW(5,fb,pb); break;
        case 6: SW(6,fb,pb); break; case 7: SW(7,fb,pb); break;
        default: SW(8,fb,pb); break;
      }
    }
  }
  #undef SW
  #undef UPD

  u16* srow = s + (long)i*KS;
  #pragma unroll
  for (int r=0;r<RR;r++){
    #pragma unroll
    for (int seg=0;seg<3;seg++)
      ((u32*)(srow + r*DIN + seg*128))[l] = pk2(acc[r][seg*2], acc[r][seg*2+1]);
  }
  float cv = 0.f;
  #pragma unroll
  for (int r=0;r<RR;r++) cv = (l == r) ? cacc[r] : cv;
  if (l < 32) srow[KSU + l] = f2bf(l < RR ? cv : 0.f);
}

// ---------------- m97-style bf16 GEMM: C = A * B^T (both K-major) ----------------
// grid: x = M-tile (fast), y = N-tile  -> same-A blocks land on same XCD (id%8)
// MODE 0: O0 = relu(C) bf16, stride DH           (gemm1: x1)
// MODE 1: n<768 -> O0 = C+b0[n]; else O1 = C+b1  (gemm2: hm / selfx)
template<int MODE>
__global__ __launch_bounds__(256, 2)
void k_gemm_bt(const u16* __restrict__ A, const u16* __restrict__ B,
               int M, int N, int K,
               u16* __restrict__ O0, u16* __restrict__ O1,
               const float* __restrict__ b0, const float* __restrict__ b1)
{
  __shared__ __align__(16) u16 As[128*32];
  __shared__ __align__(16) u16 Bs[128*32];
  const int t  = threadIdx.x;
  const int wv = t >> 6;
  const int ln = t & 63;
  const int wm = wv >> 1, wn = wv & 1;
  const long m0 = (long)blockIdx.x * 128;
  const long n0 = (long)blockIdx.y * 128;

  const int srow  = ln >> 2;         // staging: lane -> row within 16-row segment
  const int skcol = (ln & 3) * 8;    // k element offset (8 bf16 = 16B)

  f32x4 acc[4][4];
  #pragma unroll
  for (int i=0;i<4;i++)
    #pragma unroll
    for (int j=0;j<4;j++) acc[i][j] = {0.f,0.f,0.f,0.f};

  const int fr = ln & 15, fq = ln >> 4;
  const int nk = K >> 5;
  for (int kb=0; kb<nk; ++kb){
    const long k0 = (long)kb * 32;
    #pragma unroll
    for (int q=0;q<2;q++){
      const int seg = wv*2 + q;
      const int row = seg*16 + srow;
      gll16(A + (m0 + row)*(long)K + k0 + skcol, &As[seg*512]);
      gll16(B + (n0 + row)*(long)K + k0 + skcol, &Bs[seg*512]);
    }
    __syncthreads();
    b16x8 av[4], bv[4];
    #pragma unroll
    for (int i=0;i<4;i++){
      av[i] = *(const b16x8*)&As[(wm*64 + i*16 + fr)*32 + fq*8];
      bv[i] = *(const b16x8*)&Bs[(wn*64 + i*16 + fr)*32 + fq*8];
    }
    #pragma unroll
    for (int i=0;i<4;i++)
      #pragma unroll
      for (int j=0;j<4;j++)
        acc[i][j] = __builtin_amdgcn_mfma_f32_16x16x32_bf16(av[i], bv[j], acc[i][j], 0, 0, 0);
    __syncthreads();
  }

  #pragma unroll
  for (int i=0;i<4;i++){
    #pragma unroll
    for (int j=0;j<4;j++){
      #pragma unroll
      for (int r=0;r<4;r++){
        const long m = m0 + wm*64 + i*16 + fq*4 + r;   // C row = quad*4+reg
        const long n = n0 + wn*64 + j*16 + fr;         // C col = lane&15
        float v = acc[i][j][r];
        if (MODE == 0){
          v = v > 0.f ? v : 0.f;
          O0[m*DH + n] = f2bf(v);
        } else {
          if (n < DH) O0[m*DH + n]      = f2bf(v + b0[n]);
          else        O1[m*DH + (n-DH)] = f2bf(v + b1[n-DH]);
        }
      }
    }
  }
}

// ---------------- phase2 + mean-pool fused ----------------
// per node i: v = relu( sum_{p in seg(i)} hm[srcp[p]] + sfx[i] ); pooled += v
// x2 never materialized. Explicit A/B prefetch slots (constant indices only).
__global__ __launch_bounds__(256, 2) void k_phase2(const u32* __restrict__ hm32,
                                                   const u32* __restrict__ sfx32,
                                                   const int* __restrict__ srcp,
                                                   const int* __restrict__ starts,
                                                   float* __restrict__ pooled){
  const int w = threadIdx.x >> 6, l = threadIdx.x & 63;
  const int i = blockIdx.x*4 + w;
  const int t = threadIdx.x;
  __shared__ float pl[DH];
  #pragma unroll
  for (int k=0;k<3;k++) pl[t + 256*k] = 0.f;
  __syncthreads();

  float a[12];
  #pragma unroll
  for (int j=0;j<12;j++) a[j] = 0.f;
  const int e0 = starts[i], np = starts[i+1] - e0;

  u32 A0=0,A1=0,A2=0,A3=0,A4=0,A5=0;
  u32 B0=0,B1=0,B2=0,B3=0,B4=0,B5=0;
  if (np > 0){
    const u32* hr = hm32 + (long)srcp[e0]*384;
    A0=hr[l]; A1=hr[64+l]; A2=hr[128+l]; A3=hr[192+l]; A4=hr[256+l]; A5=hr[320+l];
  }
  if (np > 1){
    const u32* hr = hm32 + (long)srcp[e0+1]*384;
    B0=hr[l]; B1=hr[64+l]; B2=hr[128+l]; B3=hr[192+l]; B4=hr[256+l]; B5=hr[320+l];
  }
  for (int p=0; p<np; p+=2){
    const bool h2 = (p+1 < np);
    u32 ca[6] = {A0,A1,A2,A3,A4,A5};
    u32 cb[6] = {B0,B1,B2,B3,B4,B5};
    if (p+2 < np){
      const u32* hr = hm32 + (long)srcp[e0+p+2]*384;
      A0=hr[l]; A1=hr[64+l]; A2=hr[128+l]; A3=hr[192+l]; A4=hr[256+l]; A5=hr[320+l];
    }
    if (p+3 < np){
      const u32* hr = hm32 + (long)srcp[e0+p+3]*384;
      B0=hr[l]; B1=hr[64+l]; B2=hr[128+l]; B3=hr[192+l]; B4=hr[256+l]; B5=hr[320+l];
    }
    #pragma unroll
    for (int j=0;j<6;j++){ a[2*j] += bflo(ca[j]); a[2*j+1] += bfhi(ca[j]); }
    if (h2){
      #pragma unroll
      for (int j=0;j<6;j++){ a[2*j] += bflo(cb[j]); a[2*j+1] += bfhi(cb[j]); }
    }
  }
  const u32* sr = sfx32 + (long)i*384;
  #pragma unroll
  for (int j=0;j<6;j++){
    const u32 sv = sr[l + 64*j];
    float v0 = a[2*j]   + bflo(sv);
    float v1 = a[2*j+1] + bfhi(sv);
    v0 = v0 > 0.f ? v0 : 0.f;
    v1 = v1 > 0.f ? v1 : 0.f;
    atomicAdd(&pl[2*l   + 128*j], v0);    // LDS atomic across the 4 waves
    atomicAdd(&pl[2*l+1 + 128*j], v1);
  }
  __syncthreads();
  #pragma unroll
  for (int k=0;k<3;k++) atomicAdd(&pooled[t + 256*k], pl[t + 256*k]);
}

__global__ __launch_bounds__(256) void k_final(const float* __restrict__ pooled,
                                               const float* __restrict__ oW,
                                               const float* __restrict__ ob,
                                               float* __restrict__ out){
  __shared__ float red[256];
  const int t = threadIdx.x;
  for (int c=0;c<5;c++){
    float p = 0.f;
    for (int h=t; h<DH; h+=256) p += pooled[h]*oW[c*DH + h];
    red[t] = p; __syncthreads();
    for (int o=128;o;o>>=1){ if (t<o) red[t]+=red[t+o]; __syncthreads(); }
    if (t == 0) out[c] = red[0]*(1.f/(float)NN) + ob[c];
    __syncthreads();
  }
}

// ---------------- launch ----------------
extern "C" void kernel_launch(void* const* d_in, const int* in_sizes, int n_in,
                              void* d_out, int out_size, void* d_ws, size_t ws_size,
                              hipStream_t stream)
{
  (void)in_sizes; (void)n_in; (void)out_size; (void)ws_size;
  const float* x     = (const float*)d_in[0];
  const int*   ei    = (const int*)  d_in[1];   // [2][E]: row0=src, row1=dst
  const int*   et    = (const int*)  d_in[2];
  const float* relW  = (const float*)d_in[3];
  const float* relb  = (const float*)d_in[4];
  const float* nc    = (const float*)d_in[5];
  const float* linW  = (const float*)d_in[6];
  const float* linb  = (const float*)d_in[7];
  const float* selfW = (const float*)d_in[8];
  const float* selfb = (const float*)d_in[9];
  const float* outW  = (const float*)d_in[10];
  const float* outb  = (const float*)d_in[11];
  float* out = (float*)d_out;

  // workspace layout (256B aligned); xb aliases x1 (dead until gemm1 writes it);
  // hm/sfx alias S (dead after gemm1)
  u8* w = (u8*)d_ws;
  int*   counts = (int*)(w + 0);              // 64 KB
  int*   starts = (int*)(w + 65536);          // 16385*4
  int*   cursor = (int*)(w + 131328);         // 64 KB
  int*   srcp   = (int*)(w + 196864);         // 1 MB
  int*   rp     = (int*)(w + 2294016);        // 1 MB
  u16*   Wst    = (u16*)(w + 4391168);        // 768*3488*2  = 5.36 MB
  u16*   WB     = (u16*)(w + 9748736);        // 1536*768*2  = 2.36 MB
  u16*   x1     = (u16*)(w + 12108032);       // 16384*768*2 = 25.2 MB
  u32*   xb     = (u32*)x1;                   // alias: 12.6 MB, dead before gemm1
  float* pooled = (float*)(w + 37273856);     // 3 KB
  u16*   S      = (u16*)(w + 37276928);       // 16384*3488*2 = 114.3 MB
  u16*   hm     = S;                          // alias: 25.2 MB
  u16*   sfx    = (u16*)(w + 37276928 + 25165824);

  const int* esrc = ei;
  const int* edst = ei + EE;

  hipMemsetAsync(counts, 0, NN*sizeof(int), stream);
  hipMemsetAsync(pooled, 0, DH*sizeof(float), stream);

  k_count <<<EE/256, 256, 0, stream>>>(edst, counts);
  k_scan  <<<1, 1024, 0, stream>>>(counts, starts, cursor);
  k_place <<<EE/256, 256, 0, stream>>>(esrc, edst, et, cursor, srcp, rp);
  k_convX <<<(NN*DIN/2)/256, 256, 0, stream>>>(x, xb);
  k_convW1<<<dim3(14, DH), 256, 0, stream>>>(relW, relb, Wst);
  k_convW2<<<(2*DH*DH)/256, 256, 0, stream>>>(linW, selfW, WB);
  k_phase1f<<<NN/4, 256, 0, stream>>>(xb, srcp, rp, nc, starts, S);
  k_gemm_bt<0><<<dim3(NN/128, DH/128), 256, 0, stream>>>(
      S, Wst, NN, DH, KS, x1, (u16*)nullptr, (const float*)nullptr, (const float*)nullptr);
  k_gemm_bt<1><<<dim3(NN/128, 2*DH/128), 256, 0, stream>>>(
      x1, WB, NN, 2*DH, DH, hm, sfx, linb, selfb);
  k_phase2<<<NN/4, 256, 0, stream>>>((const u32*)hm, (const u32*)sfx, srcp, starts, pooled);
  k_final <<<1, 256, 0, stream>>>(pooled, outW, outb, out);
}

// Round 6
// 545.618 us; speedup vs baseline: 4.8052x; 1.2472x over previous
//
#include <hip/hip_runtime.h>

typedef unsigned char  u8;
typedef unsigned short u16;
typedef unsigned int   u32;

#define NN   16384     // nodes
#define EE   262144    // edges
#define RR   9         // relations
#define DIN  384
#define DH   768
#define KSU  3456      // RR*DIN
#define KS   3488      // KSU + 9 cnt cols + pad to 32

typedef float  f32x4 __attribute__((ext_vector_type(4)));
typedef float  f32x2 __attribute__((ext_vector_type(2)));
typedef __bf16 b16x8 __attribute__((ext_vector_type(8)));

__device__ __forceinline__ u16 f2bf(float f){
  u32 u = __builtin_bit_cast(u32, f);
  u += 0x7fffu + ((u >> 16) & 1u);          // RNE
  return (u16)(u >> 16);
}
__device__ __forceinline__ float bf2f(u16 h){
  u32 u = ((u32)h) << 16;
  return __builtin_bit_cast(float, u);
}
__device__ __forceinline__ float bflo(u32 u){ return __builtin_bit_cast(float, u << 16); }
__device__ __forceinline__ float bfhi(u32 u){ return __builtin_bit_cast(float, u & 0xffff0000u); }
__device__ __forceinline__ u32 pk2(float a, float b){
  return (u32)f2bf(a) | ((u32)f2bf(b) << 16);
}
// async global->LDS, 16B per lane; LDS dest = wave-uniform base + lane*16
__device__ __forceinline__ void gll16(const void* g, void* l){
  __builtin_amdgcn_global_load_lds((const __attribute__((address_space(1))) void*)g,
                                   (__attribute__((address_space(3))) void*)l, 16, 0, 0);
}

// ---------------- CSR build ----------------
__global__ void k_count(const int* __restrict__ dst, int* __restrict__ counts){
  const int e = blockIdx.x*256 + threadIdx.x;
  if (e < EE) atomicAdd(&counts[dst[e]], 1);
}

__global__ __launch_bounds__(1024) void k_scan(const int* __restrict__ counts,
                                               int* __restrict__ starts,
                                               int* __restrict__ cursor){
  __shared__ int tot[1024];
  const int t = threadIdx.x;
  int loc[16]; int s = 0;
  #pragma unroll
  for (int j=0;j<16;j++){ loc[j] = counts[t*16+j]; s += loc[j]; }
  tot[t] = s;
  __syncthreads();
  for (int o=1;o<1024;o<<=1){
    int v = (t>=o) ? tot[t-o] : 0;
    __syncthreads();
    tot[t] += v;
    __syncthreads();
  }
  int run = tot[t] - s;  // exclusive prefix
  #pragma unroll
  for (int j=0;j<16;j++){ starts[t*16+j] = run; cursor[t*16+j] = run; run += loc[j]; }
  if (t == 1023) starts[NN] = run;
}

// scatter edges into CSR order; emit pre-gathered src/dst/rtype arrays
__global__ void k_place(const int* __restrict__ src, const int* __restrict__ dst,
                        const int* __restrict__ et, int* __restrict__ cursor,
                        int* __restrict__ srcp, int* __restrict__ dstp,
                        int* __restrict__ rp){
  const int e = blockIdx.x*256 + threadIdx.x;
  if (e < EE){
    const int p = atomicAdd(&cursor[dst[e]], 1);
    srcp[p] = src[e];
    dstp[p] = dst[e];
    rp[p]   = et[e];
  }
}

// ---------------- conversions to bf16 ----------------
__global__ void k_convX(const float* __restrict__ x, u32* __restrict__ xb){
  const int idx = blockIdx.x*256 + threadIdx.x;   // pairs; NN*DIN/2 total
  const f32x2 v = ((const f32x2*)x)[idx];
  xb[idx] = pk2(v.x, v.y);
}

// W_stack[hh][k]: k<3456 -> rel_W[r=k/384][hh][k%384]; 3456..3464 -> rel_b[r][hh]; else 0
__global__ void k_convW1(const float* __restrict__ rW, const float* __restrict__ rb,
                         u16* __restrict__ Wst){
  const int hh = blockIdx.y;
  const int k  = blockIdx.x*256 + threadIdx.x;
  if (k >= KS) return;
  float v;
  if (k < KSU){ const int r = k / DIN; const int d = k - r*DIN;
                v = rW[((long)r*DH + hh)*DIN + d]; }
  else if (k < KSU + RR){ const int r = k - KSU; v = rb[(long)r*DH + hh]; }
  else v = 0.f;
  Wst[(long)hh*KS + k] = f2bf(v);
}

__global__ void k_convW2(const float* __restrict__ lW, const float* __restrict__ sW,
                         u16* __restrict__ WB){
  const int idx = blockIdx.x*256 + threadIdx.x;  // exactly 1179648 threads
  const float v = (idx < DH*DH) ? lW[idx] : sW[idx - DH*DH];
  WB[idx] = f2bf(v);
}

// ---------------- dots: one wave per CSR slot ----------------
// normp[p] = dot(x[dstp[p]], x[srcp[p]]) / nc[rp[p]]   (bf16 inputs, fp32 acc)
__global__ __launch_bounds__(256, 4) void k_dots(const u32* __restrict__ xb,
                                                 const int* __restrict__ srcp,
                                                 const int* __restrict__ dstp,
                                                 const int* __restrict__ rp,
                                                 const float* __restrict__ nc,
                                                 float* __restrict__ normp){
  const int p = blockIdx.x*4 + (threadIdx.x >> 6);
  const int l = threadIdx.x & 63;
  const u32* xs = xb + (long)srcp[p]*192;
  const u32* xd = xb + (long)dstp[p]*192;
  float s = 0.f;
  #pragma unroll
  for (int j=0;j<3;j++){
    const u32 a = xs[l + 64*j], b = xd[l + 64*j];
    s += bflo(a)*bflo(b) + bfhi(a)*bfhi(b);
  }
  #pragma unroll
  for (int o=32;o;o>>=1) s += __shfl_xor(s, o);
  if (l == 0) normp[p] = s / nc[rp[p]];
}

// ---------------- phase1: wave per dst node, streaming axpy, VGPR acc ----
// s[i, r*384+d] = sum_{p in seg(i)} normp[p] * x[srcp[p], d]; s[i,3456+r] = sum normp
// launch_bounds(256,3): cap 170 VGPR — live set ~85, no spill (R4/R5 lesson:
// (256,4)'s 128 cap spilled the 54-reg accumulator -> GBs of scratch traffic).
// 3-slot explicit prefetch ring, constant register indices only.
__global__ __launch_bounds__(256, 3) void k_phase1f(const u32* __restrict__ xb,
                                                    const int* __restrict__ srcp,
                                                    const int* __restrict__ rp,
                                                    const float* __restrict__ normp,
                                                    const int* __restrict__ starts,
                                                    u16* __restrict__ s){
  const int w = threadIdx.x >> 6, l = threadIdx.x & 63;
  const int i = blockIdx.x*4 + w;
  float acc[RR][6];
  float cacc[RR];
  #pragma unroll
  for (int r=0;r<RR;r++){
    cacc[r] = 0.f;
    #pragma unroll
    for (int j=0;j<6;j++) acc[r][j] = 0.f;
  }
  const int e0 = starts[i], np = starts[i+1] - e0;

  u32 A0=0,A1=0,A2=0,B0=0,B1=0,B2=0,C0=0,C1=0,C2=0;
  float nA=0.f,nB=0.f,nC=0.f; int Ar=0,Br=0,Cr=0;

  #define LOADSLOT(S0,S1,S2,NR,RV,idx) { \
    const u32* xs_ = xb + (long)srcp[idx]*192; \
    S0 = xs_[l]; S1 = xs_[64+l]; S2 = xs_[128+l]; \
    NR = normp[idx]; RV = rp[idx]; }
  #define CONSUME(S0,S1,S2,NR,RV) { \
    const float f0=bflo(S0), f1=bfhi(S0), f2=bflo(S1), \
                f3=bfhi(S1), f4=bflo(S2), f5=bfhi(S2); \
    const float nm = NR; \
    switch (RV){ \
      case 0: cacc[0]+=nm; acc[0][0]+=nm*f0; acc[0][1]+=nm*f1; acc[0][2]+=nm*f2; acc[0][3]+=nm*f3; acc[0][4]+=nm*f4; acc[0][5]+=nm*f5; break; \
      case 1: cacc[1]+=nm; acc[1][0]+=nm*f0; acc[1][1]+=nm*f1; acc[1][2]+=nm*f2; acc[1][3]+=nm*f3; acc[1][4]+=nm*f4; acc[1][5]+=nm*f5; break; \
      case 2: cacc[2]+=nm; acc[2][0]+=nm*f0; acc[2][1]+=nm*f1; acc[2][2]+=nm*f2; acc[2][3]+=nm*f3; acc[2][4]+=nm*f4; acc[2][5]+=nm*f5; break; \
      case 3: cacc[3]+=nm; acc[3][0]+=nm*f0; acc[3][1]+=nm*f1; acc[3][2]+=nm*f2; acc[3][3]+=nm*f3; acc[3][4]+=nm*f4; acc[3][5]+=nm*f5; break; \
      case 4: cacc[4]+=nm; acc[4][0]+=nm*f0; acc[4][1]+=nm*f1; acc[4][2]+=nm*f2; acc[4][3]+=nm*f3; acc[4][4]+=nm*f4; acc[4][5]+=nm*f5; break; \
      case 5: cacc[5]+=nm; acc[5][0]+=nm*f0; acc[5][1]+=nm*f1; acc[5][2]+=nm*f2; acc[5][3]+=nm*f3; acc[5][4]+=nm*f4; acc[5][5]+=nm*f5; break; \
      case 6: cacc[6]+=nm; acc[6][0]+=nm*f0; acc[6][1]+=nm*f1; acc[6][2]+=nm*f2; acc[6][3]+=nm*f3; acc[6][4]+=nm*f4; acc[6][5]+=nm*f5; break; \
      case 7: cacc[7]+=nm; acc[7][0]+=nm*f0; acc[7][1]+=nm*f1; acc[7][2]+=nm*f2; acc[7][3]+=nm*f3; acc[7][4]+=nm*f4; acc[7][5]+=nm*f5; break; \
      default:cacc[8]+=nm; acc[8][0]+=nm*f0; acc[8][1]+=nm*f1; acc[8][2]+=nm*f2; acc[8][3]+=nm*f3; acc[8][4]+=nm*f4; acc[8][5]+=nm*f5; break; \
    } }

  if (np > 0) LOADSLOT(A0,A1,A2,nA,Ar,e0)
  if (np > 1) LOADSLOT(B0,B1,B2,nB,Br,e0+1)
  if (np > 2) LOADSLOT(C0,C1,C2,nC,Cr,e0+2)

  for (int p=0; p<np; p+=3){
    CONSUME(A0,A1,A2,nA,Ar)
    if (p+3 < np) LOADSLOT(A0,A1,A2,nA,Ar,e0+p+3)
    if (p+1 < np){
      CONSUME(B0,B1,B2,nB,Br)
      if (p+4 < np) LOADSLOT(B0,B1,B2,nB,Br,e0+p+4)
    }
    if (p+2 < np){
      CONSUME(C0,C1,C2,nC,Cr)
      if (p+5 < np) LOADSLOT(C0,C1,C2,nC,Cr,e0+p+5)
    }
  }
  #undef CONSUME
  #undef LOADSLOT

  u16* srow = s + (long)i*KS;
  #pragma unroll
  for (int r=0;r<RR;r++){
    #pragma unroll
    for (int seg=0;seg<3;seg++)
      ((u32*)(srow + r*DIN + seg*128))[l] = pk2(acc[r][seg*2], acc[r][seg*2+1]);
  }
  float cv = 0.f;
  #pragma unroll
  for (int r=0;r<RR;r++) cv = (l == r) ? cacc[r] : cv;
  if (l < 32) srow[KSU + l] = f2bf(l < RR ? cv : 0.f);
}

// ---------------- m97-style bf16 GEMM: C = A * B^T (both K-major) ----------------
// grid: x = M-tile (fast), y = N-tile  -> same-A blocks land on same XCD (id%8)
// MODE 0: O0 = relu(C) bf16, stride DH           (gemm1: x1)
// MODE 1: n<768 -> O0 = C+b0[n]; else O1 = C+b1  (gemm2: hm / selfx)
template<int MODE>
__global__ __launch_bounds__(256, 2)
void k_gemm_bt(const u16* __restrict__ A, const u16* __restrict__ B,
               int M, int N, int K,
               u16* __restrict__ O0, u16* __restrict__ O1,
               const float* __restrict__ b0, const float* __restrict__ b1)
{
  __shared__ __align__(16) u16 As[128*32];
  __shared__ __align__(16) u16 Bs[128*32];
  const int t  = threadIdx.x;
  const int wv = t >> 6;
  const int ln = t & 63;
  const int wm = wv >> 1, wn = wv & 1;
  const long m0 = (long)blockIdx.x * 128;
  const long n0 = (long)blockIdx.y * 128;

  const int srow  = ln >> 2;         // staging: lane -> row within 16-row segment
  const int skcol = (ln & 3) * 8;    // k element offset (8 bf16 = 16B)

  f32x4 acc[4][4];
  #pragma unroll
  for (int i=0;i<4;i++)
    #pragma unroll
    for (int j=0;j<4;j++) acc[i][j] = {0.f,0.f,0.f,0.f};

  const int fr = ln & 15, fq = ln >> 4;
  const int nk = K >> 5;
  for (int kb=0; kb<nk; ++kb){
    const long k0 = (long)kb * 32;
    #pragma unroll
    for (int q=0;q<2;q++){
      const int seg = wv*2 + q;
      const int row = seg*16 + srow;
      gll16(A + (m0 + row)*(long)K + k0 + skcol, &As[seg*512]);
      gll16(B + (n0 + row)*(long)K + k0 + skcol, &Bs[seg*512]);
    }
    __syncthreads();
    b16x8 av[4], bv[4];
    #pragma unroll
    for (int i=0;i<4;i++){
      av[i] = *(const b16x8*)&As[(wm*64 + i*16 + fr)*32 + fq*8];
      bv[i] = *(const b16x8*)&Bs[(wn*64 + i*16 + fr)*32 + fq*8];
    }
    #pragma unroll
    for (int i=0;i<4;i++)
      #pragma unroll
      for (int j=0;j<4;j++)
        acc[i][j] = __builtin_amdgcn_mfma_f32_16x16x32_bf16(av[i], bv[j], acc[i][j], 0, 0, 0);
    __syncthreads();
  }

  #pragma unroll
  for (int i=0;i<4;i++){
    #pragma unroll
    for (int j=0;j<4;j++){
      #pragma unroll
      for (int r=0;r<4;r++){
        const long m = m0 + wm*64 + i*16 + fq*4 + r;   // C row = quad*4+reg
        const long n = n0 + wn*64 + j*16 + fr;         // C col = lane&15
        float v = acc[i][j][r];
        if (MODE == 0){
          v = v > 0.f ? v : 0.f;
          O0[m*DH + n] = f2bf(v);
        } else {
          if (n < DH) O0[m*DH + n]      = f2bf(v + b0[n]);
          else        O1[m*DH + (n-DH)] = f2bf(v + b1[n-DH]);
        }
      }
    }
  }
}

// ---------------- phase2 + mean-pool fused ----------------
// per node i: v = relu( sum_{p in seg(i)} hm[srcp[p]] + sfx[i] ); pooled += v
// 8 nodes/block (2 per wave, accumulated in regs), LDS block-reduce, then
// global atomics spread over 8 pooled copies (blockIdx&7) to cut contention.
__global__ __launch_bounds__(256, 4) void k_phase2(const u32* __restrict__ hm32,
                                                   const u32* __restrict__ sfx32,
                                                   const int* __restrict__ srcp,
                                                   const int* __restrict__ starts,
                                                   float* __restrict__ pooled8){
  const int w = threadIdx.x >> 6, l = threadIdx.x & 63;
  const int t = threadIdx.x;
  __shared__ float pl[DH];
  #pragma unroll
  for (int k=0;k<3;k++) pl[t + 256*k] = 0.f;
  __syncthreads();

  float po[12];
  #pragma unroll
  for (int j=0;j<12;j++) po[j] = 0.f;

  for (int q=0;q<2;q++){
    const int i = blockIdx.x*8 + w*2 + q;
    float a[12];
    #pragma unroll
    for (int j=0;j<12;j++) a[j] = 0.f;
    const int e0 = starts[i], np = starts[i+1] - e0;

    u32 A0=0,A1=0,A2=0,A3=0,A4=0,A5=0;
    u32 B0=0,B1=0,B2=0,B3=0,B4=0,B5=0;
    if (np > 0){
      const u32* hr = hm32 + (long)srcp[e0]*384;
      A0=hr[l]; A1=hr[64+l]; A2=hr[128+l]; A3=hr[192+l]; A4=hr[256+l]; A5=hr[320+l];
    }
    if (np > 1){
      const u32* hr = hm32 + (long)srcp[e0+1]*384;
      B0=hr[l]; B1=hr[64+l]; B2=hr[128+l]; B3=hr[192+l]; B4=hr[256+l]; B5=hr[320+l];
    }
    for (int p=0; p<np; p+=2){
      a[0]+=bflo(A0); a[1]+=bfhi(A0); a[2]+=bflo(A1); a[3] +=bfhi(A1);
      a[4]+=bflo(A2); a[5]+=bfhi(A2); a[6] +=bflo(A3); a[7] +=bfhi(A3);
      a[8]+=bflo(A4); a[9]+=bfhi(A4); a[10]+=bflo(A5); a[11]+=bfhi(A5);
      if (p+2 < np){
        const u32* hr = hm32 + (long)srcp[e0+p+2]*384;
        A0=hr[l]; A1=hr[64+l]; A2=hr[128+l]; A3=hr[192+l]; A4=hr[256+l]; A5=hr[320+l];
      }
      if (p+1 < np){
        a[0]+=bflo(B0); a[1]+=bfhi(B0); a[2] +=bflo(B1); a[3] +=bfhi(B1);
        a[4]+=bflo(B2); a[5]+=bfhi(B2); a[6] +=bflo(B3); a[7] +=bfhi(B3);
        a[8]+=bflo(B4); a[9]+=bfhi(B4); a[10]+=bflo(B5); a[11]+=bfhi(B5);
        if (p+3 < np){
          const u32* hr = hm32 + (long)srcp[e0+p+3]*384;
          B0=hr[l]; B1=hr[64+l]; B2=hr[128+l]; B3=hr[192+l]; B4=hr[256+l]; B5=hr[320+l];
        }
      }
    }
    const u32* sr = sfx32 + (long)i*384;
    #pragma unroll
    for (int j=0;j<6;j++){
      const u32 sv = sr[l + 64*j];
      float v0 = a[2*j]   + bflo(sv);
      float v1 = a[2*j+1] + bfhi(sv);
      po[2*j]   += v0 > 0.f ? v0 : 0.f;
      po[2*j+1] += v1 > 0.f ? v1 : 0.f;
    }
  }
  #pragma unroll
  for (int j=0;j<6;j++){
    atomicAdd(&pl[2*l   + 128*j], po[2*j]);
    atomicAdd(&pl[2*l+1 + 128*j], po[2*j+1]);
  }
  __syncthreads();
  float* pd = pooled8 + (blockIdx.x & 7)*DH;
  #pragma unroll
  for (int k=0;k<3;k++) atomicAdd(&pd[t + 256*k], pl[t + 256*k]);
}

__global__ __launch_bounds__(256) void k_final(const float* __restrict__ pooled8,
                                               const float* __restrict__ oW,
                                               const float* __restrict__ ob,
                                               float* __restrict__ out){
  __shared__ float ps[DH];
  __shared__ float red[256];
  const int t = threadIdx.x;
  for (int h=t; h<DH; h+=256){
    float s = 0.f;
    #pragma unroll
    for (int c=0;c<8;c++) s += pooled8[c*DH + h];
    ps[h] = s;
  }
  __syncthreads();
  for (int c=0;c<5;c++){
    float p = 0.f;
    for (int h=t; h<DH; h+=256) p += ps[h]*oW[c*DH + h];
    red[t] = p; __syncthreads();
    for (int o=128;o;o>>=1){ if (t<o) red[t]+=red[t+o]; __syncthreads(); }
    if (t == 0) out[c] = red[0]*(1.f/(float)NN) + ob[c];
    __syncthreads();
  }
}

// ---------------- launch ----------------
extern "C" void kernel_launch(void* const* d_in, const int* in_sizes, int n_in,
                              void* d_out, int out_size, void* d_ws, size_t ws_size,
                              hipStream_t stream)
{
  (void)in_sizes; (void)n_in; (void)out_size; (void)ws_size;
  const float* x     = (const float*)d_in[0];
  const int*   ei    = (const int*)  d_in[1];   // [2][E]: row0=src, row1=dst
  const int*   et    = (const int*)  d_in[2];
  const float* relW  = (const float*)d_in[3];
  const float* relb  = (const float*)d_in[4];
  const float* nc    = (const float*)d_in[5];
  const float* linW  = (const float*)d_in[6];
  const float* linb  = (const float*)d_in[7];
  const float* selfW = (const float*)d_in[8];
  const float* selfb = (const float*)d_in[9];
  const float* outW  = (const float*)d_in[10];
  const float* outb  = (const float*)d_in[11];
  float* out = (float*)d_out;

  // workspace layout (256B aligned); xb aliases x1 (dead until gemm1 writes it);
  // hm/sfx alias S (dead after gemm1)
  u8* w = (u8*)d_ws;
  int*   counts  = (int*)(w + 0);              // 64 KB
  int*   starts  = (int*)(w + 65536);          // 16385*4
  int*   cursor  = (int*)(w + 131328);         // 64 KB
  int*   srcp    = (int*)(w + 196864);         // 1 MB
  int*   dstp    = (int*)(w + 1245440);        // 1 MB
  int*   rp      = (int*)(w + 2294016);        // 1 MB
  float* normp   = (float*)(w + 3342592);      // 1 MB
  u16*   Wst     = (u16*)(w + 4391168);        // 768*3488*2  = 5.36 MB
  u16*   WB      = (u16*)(w + 9748736);        // 1536*768*2  = 2.36 MB
  u16*   x1      = (u16*)(w + 12108032);       // 16384*768*2 = 25.2 MB
  u32*   xb      = (u32*)x1;                   // alias: 12.6 MB, dead before gemm1
  float* pooled8 = (float*)(w + 37273856);     // 8*768*4 = 24.6 KB
  u16*   S       = (u16*)(w + 37298432);       // 16384*3488*2 = 114.3 MB
  u16*   hm      = S;                          // alias: 25.2 MB
  u16*   sfx     = (u16*)(w + 37298432 + 25165824);

  const int* esrc = ei;
  const int* edst = ei + EE;

  hipMemsetAsync(counts, 0, NN*sizeof(int), stream);
  hipMemsetAsync(pooled8, 0, 8*DH*sizeof(float), stream);

  k_count <<<EE/256, 256, 0, stream>>>(edst, counts);
  k_scan  <<<1, 1024, 0, stream>>>(counts, starts, cursor);
  k_place <<<EE/256, 256, 0, stream>>>(esrc, edst, et, cursor, srcp, dstp, rp);
  k_convX <<<(NN*DIN/2)/256, 256, 0, stream>>>(x, xb);
  k_convW1<<<dim3(14, DH), 256, 0, stream>>>(relW, relb, Wst);
  k_convW2<<<(2*DH*DH)/256, 256, 0, stream>>>(linW, selfW, WB);
  k_dots  <<<EE/4, 256, 0, stream>>>(xb, srcp, dstp, rp, nc, normp);
  k_phase1f<<<NN/4, 256, 0, stream>>>(xb, srcp, rp, normp, starts, S);
  k_gemm_bt<0><<<dim3(NN/128, DH/128), 256, 0, stream>>>(
      S, Wst, NN, DH, KS, x1, (u16*)nullptr, (const float*)nullptr, (const float*)nullptr);
  k_gemm_bt<1><<<dim3(NN/128, 2*DH/128), 256, 0, stream>>>(
      x1, WB, NN, 2*DH, DH, hm, sfx, linb, selfb);
  k_phase2<<<NN/8, 256, 0, stream>>>((const u32*)hm, (const u32*)sfx, srcp, starts, pooled8);
  k_final <<<1, 256, 0, stream>>>(pooled8, outW, outb, out);
}

// Round 7
// 542.663 us; speedup vs baseline: 4.8313x; 1.0054x over previous
//
#include <hip/hip_runtime.h>

typedef unsigned char  u8;
typedef unsigned short u16;
typedef unsigned int   u32;

#define NN   16384     // nodes
#define EE   262144    // edges
#define RR   9         // relations
#define DIN  384
#define DH   768
#define KSU  3456      // RR*DIN
#define KS   3488      // KSU + 9 cnt cols + pad to 32

typedef float  f32x4 __attribute__((ext_vector_type(4)));
typedef float  f32x2 __attribute__((ext_vector_type(2)));
typedef __bf16 b16x8 __attribute__((ext_vector_type(8)));

__device__ __forceinline__ u16 f2bf(float f){
  u32 u = __builtin_bit_cast(u32, f);
  u += 0x7fffu + ((u >> 16) & 1u);          // RNE
  return (u16)(u >> 16);
}
__device__ __forceinline__ float bf2f(u16 h){
  u32 u = ((u32)h) << 16;
  return __builtin_bit_cast(float, u);
}
__device__ __forceinline__ float bflo(u32 u){ return __builtin_bit_cast(float, u << 16); }
__device__ __forceinline__ float bfhi(u32 u){ return __builtin_bit_cast(float, u & 0xffff0000u); }
__device__ __forceinline__ u32 pk2(float a, float b){
  return (u32)f2bf(a) | ((u32)f2bf(b) << 16);
}
// async global->LDS, 16B per lane; LDS dest = wave-uniform base + lane*16
__device__ __forceinline__ void gll16(const void* g, void* l){
  __builtin_amdgcn_global_load_lds((const __attribute__((address_space(1))) void*)g,
                                   (__attribute__((address_space(3))) void*)l, 16, 0, 0);
}

// ---------------- CSR build ----------------
__global__ void k_count(const int* __restrict__ dst, int* __restrict__ counts){
  const int e = blockIdx.x*256 + threadIdx.x;
  if (e < EE) atomicAdd(&counts[dst[e]], 1);
}

__global__ __launch_bounds__(1024) void k_scan(const int* __restrict__ counts,
                                               int* __restrict__ starts,
                                               int* __restrict__ cursor){
  __shared__ int tot[1024];
  const int t = threadIdx.x;
  int loc[16]; int s = 0;
  #pragma unroll
  for (int j=0;j<16;j++){ loc[j] = counts[t*16+j]; s += loc[j]; }
  tot[t] = s;
  __syncthreads();
  for (int o=1;o<1024;o<<=1){
    int v = (t>=o) ? tot[t-o] : 0;
    __syncthreads();
    tot[t] += v;
    __syncthreads();
  }
  int run = tot[t] - s;  // exclusive prefix
  #pragma unroll
  for (int j=0;j<16;j++){ starts[t*16+j] = run; cursor[t*16+j] = run; run += loc[j]; }
  if (t == 1023) starts[NN] = run;
}

// scatter edges into CSR order; emit pre-gathered src/dst/rtype arrays
__global__ void k_place(const int* __restrict__ src, const int* __restrict__ dst,
                        const int* __restrict__ et, int* __restrict__ cursor,
                        int* __restrict__ srcp, int* __restrict__ dstp,
                        int* __restrict__ rp){
  const int e = blockIdx.x*256 + threadIdx.x;
  if (e < EE){
    const int p = atomicAdd(&cursor[dst[e]], 1);
    srcp[p] = src[e];
    dstp[p] = dst[e];
    rp[p]   = et[e];
  }
}

// ---------------- all bf16 conversions in ONE kernel (region-split) --------
// region 0: xb  = bf16(x) packed pairs                (NN*DIN/2 u32)
// region 1: Wst[hh][k] stacked rel_W/rel_b (bf16)     (DH*KS elems)
// region 2: WB  = [mp_lin_W; mp_self_W] (bf16)        (2*DH*DH elems)
#define NXP (NN*DIN/2)       // 3145728
#define NW1 (DH*KS)          // 2678784
#define NW2 (2*DH*DH)        // 1179648
__global__ __launch_bounds__(256) void k_conv(const float* __restrict__ x,
                                              const float* __restrict__ rW,
                                              const float* __restrict__ rb,
                                              const float* __restrict__ lW,
                                              const float* __restrict__ sW,
                                              u32* __restrict__ xb,
                                              u16* __restrict__ Wst,
                                              u16* __restrict__ WB){
  long j = (long)blockIdx.x*256 + threadIdx.x;
  if (j < NXP){
    const f32x2 v = ((const f32x2*)x)[j];
    xb[j] = pk2(v.x, v.y);
    return;
  }
  j -= NXP;
  if (j < NW1){
    const int hh = (int)(j / KS);
    const int k  = (int)(j - (long)hh*KS);
    float v;
    if (k < KSU){ const int r = k / DIN; const int d = k - r*DIN;
                  v = rW[((long)r*DH + hh)*DIN + d]; }
    else if (k < KSU + RR){ const int r = k - KSU; v = rb[(long)r*DH + hh]; }
    else v = 0.f;
    Wst[(long)hh*KS + k] = f2bf(v);
    return;
  }
  j -= NW1;
  const float v = (j < DH*DH) ? lW[j] : sW[j - DH*DH];
  WB[j] = f2bf(v);
}

// ---------------- dots: one wave per CSR slot ----------------
// normp[p] = dot(x[dstp[p]], x[srcp[p]]) / nc[rp[p]]   (bf16 inputs, fp32 acc)
__global__ __launch_bounds__(256, 4) void k_dots(const u32* __restrict__ xb,
                                                 const int* __restrict__ srcp,
                                                 const int* __restrict__ dstp,
                                                 const int* __restrict__ rp,
                                                 const float* __restrict__ nc,
                                                 float* __restrict__ normp){
  const int p = blockIdx.x*4 + (threadIdx.x >> 6);
  const int l = threadIdx.x & 63;
  const u32* xs = xb + (long)srcp[p]*192;
  const u32* xd = xb + (long)dstp[p]*192;
  float s = 0.f;
  #pragma unroll
  for (int j=0;j<3;j++){
    const u32 a = xs[l + 64*j], b = xd[l + 64*j];
    s += bflo(a)*bflo(b) + bfhi(a)*bfhi(b);
  }
  #pragma unroll
  for (int o=32;o;o>>=1) s += __shfl_xor(s, o);
  if (l == 0) normp[p] = s / nc[rp[p]];
}

// ---------------- phase1: wave per dst node, streaming axpy, VGPR acc ----
// s[i, r*384+d] = sum_{p in seg(i)} normp[p] * x[srcp[p], d]; s[i,3456+r] = sum normp
// launch_bounds(256,3): cap 170 VGPR — live set ~85, no spill (R4/R5 lesson:
// (256,4)'s 128 cap spilled the 54-reg accumulator -> GBs of scratch traffic).
// 3-slot explicit prefetch ring, constant register indices only.
__global__ __launch_bounds__(256, 3) void k_phase1f(const u32* __restrict__ xb,
                                                    const int* __restrict__ srcp,
                                                    const int* __restrict__ rp,
                                                    const float* __restrict__ normp,
                                                    const int* __restrict__ starts,
                                                    u16* __restrict__ s){
  const int w = threadIdx.x >> 6, l = threadIdx.x & 63;
  const int i = blockIdx.x*4 + w;
  float acc[RR][6];
  float cacc[RR];
  #pragma unroll
  for (int r=0;r<RR;r++){
    cacc[r] = 0.f;
    #pragma unroll
    for (int j=0;j<6;j++) acc[r][j] = 0.f;
  }
  const int e0 = starts[i], np = starts[i+1] - e0;

  u32 A0=0,A1=0,A2=0,B0=0,B1=0,B2=0,C0=0,C1=0,C2=0;
  float nA=0.f,nB=0.f,nC=0.f; int Ar=0,Br=0,Cr=0;

  #define LOADSLOT(S0,S1,S2,NR,RV,idx) { \
    const u32* xs_ = xb + (long)srcp[idx]*192; \
    S0 = xs_[l]; S1 = xs_[64+l]; S2 = xs_[128+l]; \
    NR = normp[idx]; RV = rp[idx]; }
  #define CONSUME(S0,S1,S2,NR,RV) { \
    const float f0=bflo(S0), f1=bfhi(S0), f2=bflo(S1), \
                f3=bfhi(S1), f4=bflo(S2), f5=bfhi(S2); \
    const float nm = NR; \
    switch (RV){ \
      case 0: cacc[0]+=nm; acc[0][0]+=nm*f0; acc[0][1]+=nm*f1; acc[0][2]+=nm*f2; acc[0][3]+=nm*f3; acc[0][4]+=nm*f4; acc[0][5]+=nm*f5; break; \
      case 1: cacc[1]+=nm; acc[1][0]+=nm*f0; acc[1][1]+=nm*f1; acc[1][2]+=nm*f2; acc[1][3]+=nm*f3; acc[1][4]+=nm*f4; acc[1][5]+=nm*f5; break; \
      case 2: cacc[2]+=nm; acc[2][0]+=nm*f0; acc[2][1]+=nm*f1; acc[2][2]+=nm*f2; acc[2][3]+=nm*f3; acc[2][4]+=nm*f4; acc[2][5]+=nm*f5; break; \
      case 3: cacc[3]+=nm; acc[3][0]+=nm*f0; acc[3][1]+=nm*f1; acc[3][2]+=nm*f2; acc[3][3]+=nm*f3; acc[3][4]+=nm*f4; acc[3][5]+=nm*f5; break; \
      case 4: cacc[4]+=nm; acc[4][0]+=nm*f0; acc[4][1]+=nm*f1; acc[4][2]+=nm*f2; acc[4][3]+=nm*f3; acc[4][4]+=nm*f4; acc[4][5]+=nm*f5; break; \
      case 5: cacc[5]+=nm; acc[5][0]+=nm*f0; acc[5][1]+=nm*f1; acc[5][2]+=nm*f2; acc[5][3]+=nm*f3; acc[5][4]+=nm*f4; acc[5][5]+=nm*f5; break; \
      case 6: cacc[6]+=nm; acc[6][0]+=nm*f0; acc[6][1]+=nm*f1; acc[6][2]+=nm*f2; acc[6][3]+=nm*f3; acc[6][4]+=nm*f4; acc[6][5]+=nm*f5; break; \
      case 7: cacc[7]+=nm; acc[7][0]+=nm*f0; acc[7][1]+=nm*f1; acc[7][2]+=nm*f2; acc[7][3]+=nm*f3; acc[7][4]+=nm*f4; acc[7][5]+=nm*f5; break; \
      default:cacc[8]+=nm; acc[8][0]+=nm*f0; acc[8][1]+=nm*f1; acc[8][2]+=nm*f2; acc[8][3]+=nm*f3; acc[8][4]+=nm*f4; acc[8][5]+=nm*f5; break; \
    } }

  if (np > 0) LOADSLOT(A0,A1,A2,nA,Ar,e0)
  if (np > 1) LOADSLOT(B0,B1,B2,nB,Br,e0+1)
  if (np > 2) LOADSLOT(C0,C1,C2,nC,Cr,e0+2)

  for (int p=0; p<np; p+=3){
    CONSUME(A0,A1,A2,nA,Ar)
    if (p+3 < np) LOADSLOT(A0,A1,A2,nA,Ar,e0+p+3)
    if (p+1 < np){
      CONSUME(B0,B1,B2,nB,Br)
      if (p+4 < np) LOADSLOT(B0,B1,B2,nB,Br,e0+p+4)
    }
    if (p+2 < np){
      CONSUME(C0,C1,C2,nC,Cr)
      if (p+5 < np) LOADSLOT(C0,C1,C2,nC,Cr,e0+p+5)
    }
  }
  #undef CONSUME
  #undef LOADSLOT

  u16* srow = s + (long)i*KS;
  #pragma unroll
  for (int r=0;r<RR;r++){
    #pragma unroll
    for (int seg=0;seg<3;seg++)
      ((u32*)(srow + r*DIN + seg*128))[l] = pk2(acc[r][seg*2], acc[r][seg*2+1]);
  }
  float cv = 0.f;
  #pragma unroll
  for (int r=0;r<RR;r++) cv = (l == r) ? cacc[r] : cv;
  if (l < 32) srow[KSU + l] = f2bf(l < RR ? cv : 0.f);
}

// ---------------- m97-style bf16 GEMM: C = A * B^T (both K-major) ----------------
// grid: x = M-tile (fast), y = N-tile  -> same-A blocks land on same XCD (id%8)
// LDS chunk swizzle: physical 8-elem chunk p at row r holds logical chunk
// (p - k(r))&3, k(r) = (r + (r>>2))&3. Applied on the GLOBAL SOURCE address
// (gll16's LDS dest is forced lane-contiguous), bijective per row -> no
// correctness change; breaks the 8-way ds_read_b128 bank conflict to 2-way.
// MODE 0: O0 = relu(C) bf16, stride DH           (gemm1: x1)
// MODE 1: n<768 -> O0 = C+b0[n]; else O1 = C+b1  (gemm2: hm / selfx)
template<int MODE>
__global__ __launch_bounds__(256, 2)
void k_gemm_bt(const u16* __restrict__ A, const u16* __restrict__ B,
               int M, int N, int K,
               u16* __restrict__ O0, u16* __restrict__ O1,
               const float* __restrict__ b0, const float* __restrict__ b1)
{
  __shared__ __align__(16) u16 As[128*32];
  __shared__ __align__(16) u16 Bs[128*32];
  const int t  = threadIdx.x;
  const int wv = t >> 6;
  const int ln = t & 63;
  const int wm = wv >> 1, wn = wv & 1;
  const long m0 = (long)blockIdx.x * 128;
  const long n0 = (long)blockIdx.y * 128;

  const int ri    = ln >> 2;                     // staging row within 16-row segment
  const int kw    = (ri + (ri >> 2)) & 3;        // swizzle key (row-local)
  const int skcol = (((ln & 3) - kw) & 3) * 8;   // logical col chunk this lane fetches

  f32x4 acc[4][4];
  #pragma unroll
  for (int i=0;i<4;i++)
    #pragma unroll
    for (int j=0;j<4;j++) acc[i][j] = {0.f,0.f,0.f,0.f};

  const int fr = ln & 15, fq = ln >> 4;
  const int kr    = (fr + (fr >> 2)) & 3;        // read-side swizzle key
  const int rdoff = ((fq + kr) & 3) * 8;         // physical chunk offset (elems)
  const int nk = K >> 5;
  for (int kb=0; kb<nk; ++kb){
    const long k0 = (long)kb * 32;
    #pragma unroll
    for (int q=0;q<2;q++){
      const int seg = wv*2 + q;
      const int row = seg*16 + ri;
      gll16(A + (m0 + row)*(long)K + k0 + skcol, &As[seg*512]);
      gll16(B + (n0 + row)*(long)K + k0 + skcol, &Bs[seg*512]);
    }
    __syncthreads();
    b16x8 av[4], bv[4];
    #pragma unroll
    for (int i=0;i<4;i++){
      av[i] = *(const b16x8*)&As[(wm*64 + i*16 + fr)*32 + rdoff];
      bv[i] = *(const b16x8*)&Bs[(wn*64 + i*16 + fr)*32 + rdoff];
    }
    #pragma unroll
    for (int i=0;i<4;i++)
      #pragma unroll
      for (int j=0;j<4;j++)
        acc[i][j] = __builtin_amdgcn_mfma_f32_16x16x32_bf16(av[i], bv[j], acc[i][j], 0, 0, 0);
    __syncthreads();
  }

  #pragma unroll
  for (int i=0;i<4;i++){
    #pragma unroll
    for (int j=0;j<4;j++){
      #pragma unroll
      for (int r=0;r<4;r++){
        const long m = m0 + wm*64 + i*16 + fq*4 + r;   // C row = quad*4+reg
        const long n = n0 + wn*64 + j*16 + fr;         // C col = lane&15
        float v = acc[i][j][r];
        if (MODE == 0){
          v = v > 0.f ? v : 0.f;
          O0[m*DH + n] = f2bf(v);
        } else {
          if (n < DH) O0[m*DH + n]      = f2bf(v + b0[n]);
          else        O1[m*DH + (n-DH)] = f2bf(v + b1[n-DH]);
        }
      }
    }
  }
}

// ---------------- phase2 + mean-pool fused ----------------
// per node i: v = relu( sum_{p in seg(i)} hm[srcp[p]] + sfx[i] ); pooled += v
// 8 nodes/block (2 per wave, accumulated in regs), LDS block-reduce, then
// global atomics spread over 8 pooled copies (blockIdx&7) to cut contention.
__global__ __launch_bounds__(256, 4) void k_phase2(const u32* __restrict__ hm32,
                                                   const u32* __restrict__ sfx32,
                                                   const int* __restrict__ srcp,
                                                   const int* __restrict__ starts,
                                                   float* __restrict__ pooled8){
  const int w = threadIdx.x >> 6, l = threadIdx.x & 63;
  const int t = threadIdx.x;
  __shared__ float pl[DH];
  #pragma unroll
  for (int k=0;k<3;k++) pl[t + 256*k] = 0.f;
  __syncthreads();

  float po[12];
  #pragma unroll
  for (int j=0;j<12;j++) po[j] = 0.f;

  for (int q=0;q<2;q++){
    const int i = blockIdx.x*8 + w*2 + q;
    float a[12];
    #pragma unroll
    for (int j=0;j<12;j++) a[j] = 0.f;
    const int e0 = starts[i], np = starts[i+1] - e0;

    u32 A0=0,A1=0,A2=0,A3=0,A4=0,A5=0;
    u32 B0=0,B1=0,B2=0,B3=0,B4=0,B5=0;
    if (np > 0){
      const u32* hr = hm32 + (long)srcp[e0]*384;
      A0=hr[l]; A1=hr[64+l]; A2=hr[128+l]; A3=hr[192+l]; A4=hr[256+l]; A5=hr[320+l];
    }
    if (np > 1){
      const u32* hr = hm32 + (long)srcp[e0+1]*384;
      B0=hr[l]; B1=hr[64+l]; B2=hr[128+l]; B3=hr[192+l]; B4=hr[256+l]; B5=hr[320+l];
    }
    for (int p=0; p<np; p+=2){
      a[0]+=bflo(A0); a[1]+=bfhi(A0); a[2]+=bflo(A1); a[3] +=bfhi(A1);
      a[4]+=bflo(A2); a[5]+=bfhi(A2); a[6] +=bflo(A3); a[7] +=bfhi(A3);
      a[8]+=bflo(A4); a[9]+=bfhi(A4); a[10]+=bflo(A5); a[11]+=bfhi(A5);
      if (p+2 < np){
        const u32* hr = hm32 + (long)srcp[e0+p+2]*384;
        A0=hr[l]; A1=hr[64+l]; A2=hr[128+l]; A3=hr[192+l]; A4=hr[256+l]; A5=hr[320+l];
      }
      if (p+1 < np){
        a[0]+=bflo(B0); a[1]+=bfhi(B0); a[2] +=bflo(B1); a[3] +=bfhi(B1);
        a[4]+=bflo(B2); a[5]+=bfhi(B2); a[6] +=bflo(B3); a[7] +=bfhi(B3);
        a[8]+=bflo(B4); a[9]+=bfhi(B4); a[10]+=bflo(B5); a[11]+=bfhi(B5);
        if (p+3 < np){
          const u32* hr = hm32 + (long)srcp[e0+p+3]*384;
          B0=hr[l]; B1=hr[64+l]; B2=hr[128+l]; B3=hr[192+l]; B4=hr[256+l]; B5=hr[320+l];
        }
      }
    }
    const u32* sr = sfx32 + (long)i*384;
    #pragma unroll
    for (int j=0;j<6;j++){
      const u32 sv = sr[l + 64*j];
      float v0 = a[2*j]   + bflo(sv);
      float v1 = a[2*j+1] + bfhi(sv);
      po[2*j]   += v0 > 0.f ? v0 : 0.f;
      po[2*j+1] += v1 > 0.f ? v1 : 0.f;
    }
  }
  #pragma unroll
  for (int j=0;j<6;j++){
    atomicAdd(&pl[2*l   + 128*j], po[2*j]);
    atomicAdd(&pl[2*l+1 + 128*j], po[2*j+1]);
  }
  __syncthreads();
  float* pd = pooled8 + (blockIdx.x & 7)*DH;
  #pragma unroll
  for (int k=0;k<3;k++) atomicAdd(&pd[t + 256*k], pl[t + 256*k]);
}

__global__ __launch_bounds__(256) void k_final(const float* __restrict__ pooled8,
                                               const float* __restrict__ oW,
                                               const float* __restrict__ ob,
                                               float* __restrict__ out){
  __shared__ float ps[DH];
  __shared__ float red[256];
  const int t = threadIdx.x;
  for (int h=t; h<DH; h+=256){
    float s = 0.f;
    #pragma unroll
    for (int c=0;c<8;c++) s += pooled8[c*DH + h];
    ps[h] = s;
  }
  __syncthreads();
  for (int c=0;c<5;c++){
    float p = 0.f;
    for (int h=t; h<DH; h+=256) p += ps[h]*oW[c*DH + h];
    red[t] = p; __syncthreads();
    for (int o=128;o;o>>=1){ if (t<o) red[t]+=red[t+o]; __syncthreads(); }
    if (t == 0) out[c] = red[0]*(1.f/(float)NN) + ob[c];
    __syncthreads();
  }
}

// ---------------- launch ----------------
extern "C" void kernel_launch(void* const* d_in, const int* in_sizes, int n_in,
                              void* d_out, int out_size, void* d_ws, size_t ws_size,
                              hipStream_t stream)
{
  (void)in_sizes; (void)n_in; (void)out_size; (void)ws_size;
  const float* x     = (const float*)d_in[0];
  const int*   ei    = (const int*)  d_in[1];   // [2][E]: row0=src, row1=dst
  const int*   et    = (const int*)  d_in[2];
  const float* relW  = (const float*)d_in[3];
  const float* relb  = (const float*)d_in[4];
  const float* nc    = (const float*)d_in[5];
  const float* linW  = (const float*)d_in[6];
  const float* linb  = (const float*)d_in[7];
  const float* selfW = (const float*)d_in[8];
  const float* selfb = (const float*)d_in[9];
  const float* outW  = (const float*)d_in[10];
  const float* outb  = (const float*)d_in[11];
  float* out = (float*)d_out;

  // workspace layout (256B aligned); xb aliases x1 (dead until gemm1 writes it);
  // hm/sfx alias S (dead after gemm1)
  u8* w = (u8*)d_ws;
  int*   counts  = (int*)(w + 0);              // 64 KB
  int*   starts  = (int*)(w + 65536);          // 16385*4
  int*   cursor  = (int*)(w + 131328);         // 64 KB
  int*   srcp    = (int*)(w + 196864);         // 1 MB
  int*   dstp    = (int*)(w + 1245440);        // 1 MB
  int*   rp      = (int*)(w + 2294016);        // 1 MB
  float* normp   = (float*)(w + 3342592);      // 1 MB
  u16*   Wst     = (u16*)(w + 4391168);        // 768*3488*2  = 5.36 MB
  u16*   WB      = (u16*)(w + 9748736);        // 1536*768*2  = 2.36 MB
  u16*   x1      = (u16*)(w + 12108032);       // 16384*768*2 = 25.2 MB
  u32*   xb      = (u32*)x1;                   // alias: 12.6 MB, dead before gemm1
  float* pooled8 = (float*)(w + 37273856);     // 8*768*4 = 24.6 KB
  u16*   S       = (u16*)(w + 37298432);       // 16384*3488*2 = 114.3 MB
  u16*   hm      = S;                          // alias: 25.2 MB
  u16*   sfx     = (u16*)(w + 37298432 + 25165824);

  const int* esrc = ei;
  const int* edst = ei + EE;

  hipMemsetAsync(counts, 0, NN*sizeof(int), stream);
  hipMemsetAsync(pooled8, 0, 8*DH*sizeof(float), stream);

  k_count <<<EE/256, 256, 0, stream>>>(edst, counts);
  k_scan  <<<1, 1024, 0, stream>>>(counts, starts, cursor);
  k_place <<<EE/256, 256, 0, stream>>>(esrc, edst, et, cursor, srcp, dstp, rp);
  k_conv  <<<(NXP + NW1 + NW2)/256, 256, 0, stream>>>(x, relW, relb, linW, selfW,
                                                      xb, Wst, WB);
  k_dots  <<<EE/4, 256, 0, stream>>>(xb, srcp, dstp, rp, nc, normp);
  k_phase1f<<<NN/4, 256, 0, stream>>>(xb, srcp, rp, normp, starts, S);
  k_gemm_bt<0><<<dim3(NN/128, DH/128), 256, 0, stream>>>(
      S, Wst, NN, DH, KS, x1, (u16*)nullptr, (const float*)nullptr, (const float*)nullptr);
  k_gemm_bt<1><<<dim3(NN/128, 2*DH/128), 256, 0, stream>>>(
      x1, WB, NN, 2*DH, DH, hm, sfx, linb, selfb);
  k_phase2<<<NN/8, 256, 0, stream>>>((const u32*)hm, (const u32*)sfx, srcp, starts, pooled8);
  k_final <<<1, 256, 0, stream>>>(pooled8, outW, outb, out);
}